// Round 11
// baseline (246.136 us; speedup 1.0000x reference)
//
#include <hip/hip_runtime.h>
#include <hip/hip_bf16.h>
#include <hip/hip_fp16.h>

using bf16 = __hip_bfloat16;
typedef __attribute__((ext_vector_type(8))) short short8;
typedef __attribute__((ext_vector_type(4))) float f32x4;

#define NROW 4096
#define DIN  512
#define DH   256
#define DBOX 22
#define BKU  64    // proj k-tile
#define KSPL 4     // fused j-splits

#define NORM_LO 118
#define NORM_HI 130
#define WT_LO   110
#define WT_HI   126

static __device__ __forceinline__ f32x4 mfma16(short8 a, short8 b, f32x4 c) {
  return __builtin_amdgcn_mfma_f32_16x16x32_bf16(a, b, c, 0, 0, 0);
}
static __device__ __forceinline__ short8 ldg8(const bf16* p) {
  return *reinterpret_cast<const short8*>(p);
}
// async global->LDS, 16B per lane; lds ptr wave-uniform (HW adds lane*16)
static __device__ __forceinline__ void gll16(const bf16* g, void* lds) {
  __builtin_amdgcn_global_load_lds(
      (const __attribute__((address_space(1))) void*)g,
      (__attribute__((address_space(3))) void*)lds, 16, 0, 0);
}

// ---- per-block dtype detection: 0=fp32, 1=bf16, 2=fp16 -----------------------
static __device__ int detect_mode(const void* src, int lo, int hi) {
  __shared__ int cLo, cHi;
  if (threadIdx.x == 0) { cLo = 0; cHi = 0; }
  __syncthreads();
  const unsigned* w = (const unsigned*)src;
  int l = 0, h = 0;
  for (int t = threadIdx.x; t < 1024; t += 256) {
    unsigned v = w[t];
    int elo = (int)((v >> 7) & 0xFF);
    int ehi = (int)((v >> 23) & 0xFF);
    l += (elo >= lo && elo <= hi) ? 1 : 0;
    h += (ehi >= lo && ehi <= hi) ? 1 : 0;
  }
#pragma unroll
  for (int off = 32; off > 0; off >>= 1) {
    l += __shfl_down(l, off, 64);
    h += __shfl_down(h, off, 64);
  }
  if ((threadIdx.x & 63) == 0) { atomicAdd(&cLo, l); atomicAdd(&cHi, h); }
  __syncthreads();
  int lowCnt = cLo, hiCnt = cHi;
  __syncthreads();
  if (lowCnt > 700) return 1;
  if (hiCnt  > 700) return 0;
  return 2;
}

static __device__ __forceinline__ float load_as_float(const void* src, long i, int mode) {
  if (mode == 1) return __bfloat162float(((const bf16*)src)[i]);
  if (mode == 0) return ((const float*)src)[i];
  return __half2float(((const __half*)src)[i]);
}

static __device__ __forceinline__ void store_as(void* dst, long i, float v, int mode) {
  if (mode == 1)      ((bf16*)dst)[i]   = __float2bfloat16(v);
  else if (mode == 2) ((__half*)dst)[i] = __float2half(v);
  else                ((float*)dst)[i]  = v;
}

// ---------------- prep: convert x/box + weight transpose + M (22x22 Gram) -----
// blocks [0,8544): elementwise convert x, box -> bf16
// blocks [8544,8736): LDS-tiled transpose+convert W[512][256] -> WT[256][512]
// blocks [8736,8738): M[z] = WGraw @ WGraw^T in fp32 (2 blocks ONLY -- the R7
//   merge of this into 1024 p_prep blocks cost ~1GB of redundant L2 reads)
struct PrepArgs {
  const void* src[2]; bf16* dst[2];      // convert segments (x, box)
  const void* wsrc[6]; bf16* wdst[6];    // transpose segments
  const void* wgsrc[2]; float* M[2];     // raw WG -> Gram matrix
};

__global__ __launch_bounds__(256) void prep_kernel(PrepArgs a) {
  __shared__ float tile[64][65];
  if (blockIdx.x < 8544) {
    int b = blockIdx.x, seg, base;
    if (b < 8192) { seg = 0; base = b; }
    else          { seg = 1; base = b - 8192; }
    int mode = detect_mode(a.src[seg], NORM_LO, NORM_HI);
    int i = base * 256 + threadIdx.x;
    a.dst[seg][i] = __float2bfloat16(load_as_float(a.src[seg], i, mode));
  } else if (blockIdx.x < 8736) {
    int b2 = blockIdx.x - 8544;
    const int which = b2 >> 5;          // 0..5
    int rem = b2 & 31;
    const int tr = (rem & 7) * 64;
    const int tc = (rem >> 3) * 64;
    int mode = detect_mode(a.wsrc[which], WT_LO, WT_HI);
    const int rin = threadIdx.x >> 6;
    const int cin = threadIdx.x & 63;
#pragma unroll
    for (int p = 0; p < 16; ++p) {
      int r = rin + p * 4;
      tile[r][cin] = load_as_float(a.wsrc[which], (long)(tr + r) * DH + tc + cin, mode);
    }
    __syncthreads();
#pragma unroll
    for (int p = 0; p < 16; ++p) {
      int r = rin + p * 4;
      a.wdst[which][(long)(tc + r) * DIN + tr + cin] = __float2bfloat16(tile[cin][r]);
    }
  } else {
    const int z = blockIdx.x - 8736;
    int mode = detect_mode(a.wgsrc[z], WT_LO, WT_HI);
    for (int p = threadIdx.x; p < DBOX * DBOX; p += 256) {
      int r = p / DBOX, c = p % DBOX;
      float acc = 0.f;
      for (int k = 0; k < DH; ++k)
        acc += load_as_float(a.wgsrc[z], r * DH + k, mode) *
               load_as_float(a.wgsrc[z], c * DH + k, mode);
      a.M[z][p] = acc;
    }
  }
}

// ---------------- projections: C = X @ Wcat^T, Wcat = [K|Q|V] rows [768x512] ---
struct ProjArgs { const bf16* Wcat[2]; bf16* CK[2]; bf16* CQ[2]; bf16* VT[2]; };

__global__ __launch_bounds__(256, 3) void proj_kernel(const bf16* __restrict__ X, ProjArgs a) {
  const int z = blockIdx.z;
  const bf16* __restrict__ W = a.Wcat[z];
  __shared__ __align__(16) bf16 Xa[128 * BKU], Wb[128 * BKU];
  const int tid = threadIdx.x;
  const int wave = tid >> 6, lane = tid & 63;
  const int quad = lane >> 4, l16 = lane & 15;
  const int i0 = blockIdx.x * 128, n0 = blockIdx.y * 128;
  const int rw = (wave & 1) * 64, cw = (wave >> 1) * 64;

  int soff[4], grow[4], gko[4];
#pragma unroll
  for (int c = 0; c < 4; ++c) {
    int m = c * 256 + tid;
    int row = m >> 3, chunk = m & 7;
    grow[c] = row; gko[c] = chunk * 8;
    soff[c] = row * BKU + ((chunk ^ (row & 7)) * 8);
  }

  short8 pf[8];
  auto load_tiles = [&](int k0) {
#pragma unroll
    for (int c = 0; c < 4; ++c) {
      pf[c]     = ldg8(X + (long)(i0 + grow[c]) * DIN + k0 + gko[c]);
      pf[c + 4] = ldg8(W + (long)(n0 + grow[c]) * DIN + k0 + gko[c]);
    }
  };

  f32x4 acc[4][4];
#pragma unroll
  for (int p = 0; p < 4; ++p)
#pragma unroll
    for (int q = 0; q < 4; ++q) acc[p][q] = (f32x4){0,0,0,0};

  load_tiles(0);
  for (int kt = 0; kt < DIN / BKU; ++kt) {
    __syncthreads();
#pragma unroll
    for (int c = 0; c < 4; ++c) {
      *(short8*)&Xa[soff[c]] = pf[c];
      *(short8*)&Wb[soff[c]] = pf[c + 4];
    }
    __syncthreads();
    if (kt + 1 < DIN / BKU) load_tiles((kt + 1) * BKU);

#pragma unroll
    for (int kk = 0; kk < 2; ++kk) {
      short8 ax[4];
#pragma unroll
      for (int ti = 0; ti < 4; ++ti) {
        int row = rw + ti * 16 + l16;
        ax[ti] = *(const short8*)&Xa[row * BKU + (((kk * 4 + quad) ^ (row & 7)) * 8)];
      }
#pragma unroll
      for (int tj = 0; tj < 4; ++tj) {
        int row = cw + tj * 16 + l16;
        short8 bw = *(const short8*)&Wb[row * BKU + (((kk * 4 + quad) ^ (row & 7)) * 8)];
#pragma unroll
        for (int ti = 0; ti < 4; ++ti) acc[ti][tj] = mfma16(ax[ti], bw, acc[ti][tj]);
      }
    }
  }

#pragma unroll
  for (int ti = 0; ti < 4; ++ti) {
#pragma unroll
    for (int tj = 0; tj < 4; ++tj) {
#pragma unroll
      for (int r = 0; r < 4; ++r) {
        int row = i0 + rw + ti * 16 + quad * 4 + r;
        int n = n0 + cw + tj * 16 + l16;
        float sc = (n < 512) ? 0.25f : 1.0f;   // fold score 1/16 into K,Q
        bf16 v = __float2bfloat16(acc[ti][tj][r] * sc);
        if (n < 256)      a.CK[z][(long)row * DH + n] = v;
        else if (n < 512) a.CQ[z][(long)row * DH + n - 256] = v;
        else              a.VT[z][(long)(n - 512) * NROW + row] = v;
      }
    }
  }
}

// ---------------- P = box @ M / 16 (M read from global; 2KB L2-resident) ------
struct PPArgs { const float* M[2]; const bf16* Boxb; bf16* P[2]; bf16* Boxp; };

__global__ __launch_bounds__(256) void p_prep_kernel(PPArgs a) {
  const int z = blockIdx.y;
  __shared__ float Ml[DBOX * DBOX];
  for (int t = threadIdx.x; t < DBOX * DBOX; t += 256) Ml[t] = a.M[z][t];
  __syncthreads();
  int idx = blockIdx.x * 256 + threadIdx.x;
  int r = idx >> 5, c = idx & 31;
  float val = 0.f;
  if (c < DBOX) {
#pragma unroll
    for (int k = 0; k < DBOX; ++k)
      val += __bfloat162float(a.Boxb[r * DBOX + k]) * Ml[k * DBOX + c];
  }
  a.P[z][idx] = __float2bfloat16(val * 0.0625f);
  if (z == 0)
    a.Boxp[idx] = (c < DBOX) ? a.Boxb[r * DBOX + c] : __float2bfloat16(0.f);
}

// ---------------- fused score+PV: 2-barrier GLL pipeline (R11) -----------------
// R10 post-mortem: cutting LDS reads (48->32) changed nothing -> reads not
// binding; the 3 barrier events/j-tile at 1 WG/CU are (phase serialization).
// R11: full-tile Q dbuf (Qsh[2][64x256]) + Vsh[2] -> all t+1 staging issues at
// tile top; ONE counted vmcnt(2) barrier per tile (end) + ONE lgkm-only
// barrier (S publish; GLLs stay in flight across it). KQ = 32 uninterrupted
// MFMA. Gate waits counted vmcnt(10) (bb(t) has exactly 10 younger loads,
// uniform incl. t=0). LDS 145KB (1 WG/CU). kreg kept from R10.
struct FuseArgs {
  const bf16 *K[2], *Q[2], *VT[2], *P[2];
  const bf16* B;
  float* Up;       // [2 z][KSPL][NROW*DH] fp32 partials
  float* sum;
};

__global__ __launch_bounds__(512, 1) void fused_kernel(FuseArgs a) {
  const int bid = blockIdx.x;
  const int wl  = (bid & 7) * 32 + (bid >> 3);   // 256 = 8*32, bijective XCD swz
  const int ib  = wl & 31;                       // 32 i-blocks of 128 rows
  const int grp = wl >> 5;                       // 8 groups: one per XCD
  const int ks  = grp & 3;                       // KSPL == 4
  const int z   = grp >> 2;

  const bf16* __restrict__ K  = a.K[z];
  const bf16* __restrict__ Q  = a.Q[z];
  const bf16* __restrict__ VT = a.VT[z];
  const bf16* __restrict__ P  = a.P[z];
  const bf16* __restrict__ B  = a.B;
  float* __restrict__ U = a.Up + ((size_t)(z * KSPL + ks)) * NROW * DH;

  __shared__ __align__(16) bf16 Qsh[2][64 * 256];   // 2x32 KB full-k dbuf (shared)
  __shared__ __align__(16) bf16 Vsh[2][256 * 64];   // 2x32 KB dbuf (shared)
  __shared__ __align__(16) bf16 Ssh[2][64 * 64];    // 2x8 KB (per team)
  __shared__ float wsum[8];

  const int tid  = threadIdx.x;
  const int wv   = tid >> 6, lane = tid & 63;
  const int quad = lane >> 4, l16 = lane & 15;
  const int team = wv >> 2, wt = wv & 3;
  const int wi = wt >> 1, wj = wt & 1;   // team-local KQ wave grid (i32 x j32)
  const int nw = wt * 64;                // PV n-slice per wave (within team)
  const int i0t = ib * 128 + team * 64;
  const int jbase = ks * (NROW / KSPL);  // ks*1024
  const int NT = (NROW / KSPL) / 64;     // 16 j-tiles

  // hoisted per-lane GLL source offsets (element units)
  int qoff[4], voff[4];
#pragma unroll
  for (int c = 0; c < 4; ++c) {
    int m = wv * 4 + c;                  // 0..31 (Qsh buf 32KB, 512B rows)
    int b = m * 1024 + lane * 16;
    int row = b >> 9, g = (b >> 4) & 31;
    qoff[c] = row * DH + ((g ^ (row & 7)) << 3);
  }
#pragma unroll
  for (int c = 0; c < 4; ++c) {
    int m = wv * 4 + c;                  // 0..31 (Vsh buf 32KB, 128B rows)
    int b = m * 1024 + lane * 16;
    int row = b >> 7, g = (b >> 4) & 7;
    voff[c] = row * NROW + ((g ^ (row & 7)) << 3);
  }
  const bf16* Qb = Q + (long)jbase * DH;
  const bf16* Vb = VT + jbase;

  // ---- prologue (order pinned: pfr, kreg, Q(0), V(0), bb(0))
  short8 pfr[2];
#pragma unroll
  for (int ti = 0; ti < 2; ++ti)
    pfr[ti] = ldg8(P + (long)(i0t + wi * 32 + ti * 16 + l16) * 32 + quad * 8);

  short8 kreg[2][8];
#pragma unroll
  for (int ti = 0; ti < 2; ++ti)
#pragma unroll
    for (int kt = 0; kt < 8; ++kt)
      kreg[ti][kt] = ldg8(K + (long)(i0t + wi * 32 + ti * 16 + l16) * DH +
                          kt * 32 + quad * 8);
  __builtin_amdgcn_sched_barrier(0);
#pragma unroll
  for (int c = 0; c < 4; ++c)            // Q(0) -> Qsh[0]
    gll16(Qb + qoff[c], (char*)Qsh + (wv * 4 + c) * 1024);
  __builtin_amdgcn_sched_barrier(0);
#pragma unroll
  for (int c = 0; c < 4; ++c)            // V(0) -> Vsh[0]
    gll16(Vb + voff[c], (char*)Vsh + (wv * 4 + c) * 1024);
  __builtin_amdgcn_sched_barrier(0);
  short8 bbc[2], bbn[2];
#pragma unroll
  for (int tj = 0; tj < 2; ++tj)
    bbc[tj] = ldg8(B + (long)(jbase + wj * 32 + tj * 16 + l16) * 32 + quad * 8);
  __builtin_amdgcn_sched_barrier(0);

  f32x4 acc[4][4];
#pragma unroll
  for (int p = 0; p < 4; ++p)
#pragma unroll
    for (int q = 0; q < 4; ++q) acc[p][q] = (f32x4){0, 0, 0, 0};
  float lsum = 0.f;

  // prologue drain: Q(0),V(0),kreg,pfr staged; bb(0) (2) stays in flight
  asm volatile("s_waitcnt vmcnt(2) lgkmcnt(0)" ::: "memory");
  __builtin_amdgcn_sched_barrier(0);
  __builtin_amdgcn_s_barrier();
  __builtin_amdgcn_sched_barrier(0);

  int cur = 0;
  for (int t = 0; t < NT; ++t) {
    const int jnext = ((t + 1) & (NT - 1)) * 64;
    const int nxt = cur ^ 1;

    // ---- issue ALL t+1 staging (8 gll + 2 loads per wave, order pinned)
#pragma unroll
    for (int c = 0; c < 4; ++c)
      gll16(Qb + (long)jnext * DH + qoff[c], (char*)Qsh + nxt * 32768 + (wv * 4 + c) * 1024);
    __builtin_amdgcn_sched_barrier(0);
#pragma unroll
    for (int c = 0; c < 4; ++c)
      gll16(Vb + jnext + voff[c], (char*)Vsh + nxt * 32768 + (wv * 4 + c) * 1024);
    __builtin_amdgcn_sched_barrier(0);
#pragma unroll
    for (int tj = 0; tj < 2; ++tj)
      bbn[tj] = ldg8(B + (long)(jbase + jnext + wj * 32 + tj * 16 + l16) * 32 + quad * 8);
    __builtin_amdgcn_sched_barrier(0);

    // ---- KQ full k256 from Qsh[cur] + kreg (32 MFMA, uninterrupted)
    f32x4 wa[2][2];
#pragma unroll
    for (int p = 0; p < 2; ++p) { wa[p][0] = (f32x4){0,0,0,0}; wa[p][1] = (f32x4){0,0,0,0}; }
#pragma unroll
    for (int kt = 0; kt < 8; ++kt) {
      short8 qfr[2];
#pragma unroll
      for (int tj = 0; tj < 2; ++tj) {
        int row = wj * 32 + tj * 16 + l16;
        qfr[tj] = *(const short8*)((const char*)Qsh + cur * 32768 + row * 512 +
                                   (((kt * 4 + quad) ^ (row & 7)) << 4));
      }
      __builtin_amdgcn_s_setprio(1);
#pragma unroll
      for (int tj = 0; tj < 2; ++tj)
#pragma unroll
        for (int ti = 0; ti < 2; ++ti)
          wa[tj][ti] = mfma16(qfr[tj], kreg[ti][kt], wa[tj][ti]);
      __builtin_amdgcn_s_setprio(0);
    }

    // ---- gate (needs bb(t): exactly 10 younger loads = Q'4+V'4+bbn2)
    asm volatile("s_waitcnt vmcnt(10)" ::: "memory");
    f32x4 gm[2][2];
#pragma unroll
    for (int tj = 0; tj < 2; ++tj)
#pragma unroll
      for (int ti = 0; ti < 2; ++ti)
        gm[tj][ti] = mfma16(bbc[tj], pfr[ti], (f32x4){0.f, 0.f, 0.f, 0.f});

    // ---- S epilogue -> Ssh[team] (cvt_pk + b64, swizzled)
#pragma unroll
    for (int tj = 0; tj < 2; ++tj)
#pragma unroll
      for (int ti = 0; ti < 2; ++ti) {
        float sv[4];
#pragma unroll
        for (int r = 0; r < 4; ++r) {
          float g = gm[tj][ti][r];
          g = (g > 0.f) ? g : 0.f;
          float s = g * __expf(fminf(wa[tj][ti][r], 30.f));
          s = fminf(s, 1e30f);
          lsum += s;
          sv[r] = s;
        }
        unsigned w0, w1;
        asm("v_cvt_pk_bf16_f32 %0, %1, %2" : "=v"(w0) : "v"(sv[0]), "v"(sv[1]));
        asm("v_cvt_pk_bf16_f32 %0, %1, %2" : "=v"(w1) : "v"(sv[2]), "v"(sv[3]));
        int i = wi * 32 + ti * 16 + l16;
        int g16 = wj * 4 + tj * 2 + (quad >> 1);
        uint2 wvv; wvv.x = w0; wvv.y = w1;
        *(uint2*)((char*)Ssh + team * 8192 + i * 128 +
                  ((g16 ^ (i & 7)) << 4) + (quad & 1) * 8) = wvv;
      }

    // ---- barrier 1: publish Ssh. lgkm ONLY -- GLLs for t+1 stay in flight.
    asm volatile("s_waitcnt lgkmcnt(0)" ::: "memory");
    __builtin_amdgcn_sched_barrier(0);
    __builtin_amdgcn_s_barrier();
    __builtin_amdgcn_sched_barrier(0);

    // ---- PV: acc[ti][tn] += S[team](rows i) x V[cur](rows n), contract 64 j
#pragma unroll
    for (int jc = 0; jc < 2; ++jc) {
      short8 vfr[4], sfr[4];
#pragma unroll
      for (int tn = 0; tn < 4; ++tn) {
        int row = nw + tn * 16 + l16;
        vfr[tn] = *(const short8*)((const char*)Vsh + cur * 32768 + row * 128 +
                                   (((jc * 4 + quad) ^ (row & 7)) << 4));
      }
#pragma unroll
      for (int ti = 0; ti < 4; ++ti) {
        int row = ti * 16 + l16;
        sfr[ti] = *(const short8*)((const char*)Ssh + team * 8192 + row * 128 +
                                   (((jc * 4 + quad) ^ (row & 7)) << 4));
      }
      __builtin_amdgcn_s_setprio(1);
#pragma unroll
      for (int tn = 0; tn < 4; ++tn)
#pragma unroll
        for (int ti = 0; ti < 4; ++ti)
          acc[ti][tn] = mfma16(sfr[ti], vfr[tn], acc[ti][tn]);
      __builtin_amdgcn_s_setprio(0);
    }

    // ---- barrier 2: t+1 Q/V staged (2 younger = bbn); tile reads drained
    asm volatile("s_waitcnt vmcnt(2) lgkmcnt(0)" ::: "memory");
    __builtin_amdgcn_sched_barrier(0);
    __builtin_amdgcn_s_barrier();
    __builtin_amdgcn_sched_barrier(0);

    bbc[0] = bbn[0]; bbc[1] = bbn[1];
    cur = nxt;
  }

  // ---- write fp32 partial (disjoint tile, plain stores)
#pragma unroll
  for (int ti = 0; ti < 4; ++ti)
#pragma unroll
    for (int tn = 0; tn < 4; ++tn)
#pragma unroll
      for (int r = 0; r < 4; ++r)
        U[(long)(i0t + ti * 16 + quad * 4 + r) * DH + nw + tn * 16 + l16] =
            acc[ti][tn][r];

  // ---- global sum
#pragma unroll
  for (int off = 32; off > 0; off >>= 1) lsum += __shfl_down(lsum, off, 64);
  if (lane == 0) wsum[wv] = lsum;
  __syncthreads();
  if (tid == 0) {
    float s = 0.f;
#pragma unroll
    for (int w = 0; w < 8; ++w) s += wsum[w];
    atomicAdd(a.sum + z, s);
  }
}

// ---------------- epilogue: out = clamp(0.1*sum_ks(Up)/sum_b) + x --------------
__global__ __launch_bounds__(256) void epilogue_kernel(
    const void* __restrict__ xraw, const float* __restrict__ Up,
    const float* __restrict__ sums, void* __restrict__ out) {
  int mode = detect_mode(xraw, NORM_LO, NORM_HI);
  int idx = blockIdx.x * 256 + threadIdx.x;
  int r = idx >> 9, c = idx & 511;
  int z = (c < 256) ? 0 : 1;
  long e = (long)r * DH + (c & 255);
  const float* base = Up + (size_t)z * KSPL * NROW * DH;
  float u = 0.f;
#pragma unroll
  for (int ks = 0; ks < KSPL; ++ks) u += base[(size_t)ks * NROW * DH + e];
  float s = sums[z];
  float fr = u * 0.1f / s;
  fr = (fr == fr) ? fminf(fmaxf(fr, -0.05f), 0.05f) : 0.f;
  float xv = load_as_float(xraw, idx, mode);
  store_as(out, idx, xv + fr, mode);
}

// ---------------- fallback: out = cast(x), dtype-matched ----------------------
__global__ __launch_bounds__(256) void xcopy_kernel(const void* __restrict__ xraw,
                                                    void* __restrict__ out) {
  int mode = detect_mode(xraw, NORM_LO, NORM_HI);
  int idx = blockIdx.x * 256 + threadIdx.x;
  store_as(out, idx, load_as_float(xraw, idx, mode), mode);
}

// -------------------------------------------------------------------------------
extern "C" void kernel_launch(void* const* d_in, const int* in_sizes, int n_in,
                              void* d_out, int out_size, void* d_ws, size_t ws_size,
                              hipStream_t stream) {
  int ix = -1, ib = -1, wgp[2] = {-1, -1}, sixp[6] = {-1,-1,-1,-1,-1,-1};
  int nwg = 0, nsix = 0;
  for (int i = 0; i < n_in; ++i) {
    int s = in_sizes[i];
    if (s == NROW * DIN) ix = i;
    else if (s == NROW * DBOX) ib = i;
    else if (s == DIN * DH && nsix < 6) sixp[nsix++] = i;
    else if (s == DBOX * DH && nwg < 2) wgp[nwg++] = i;
  }

  if (ix < 0 || ib < 0 || nsix != 6 || nwg != 2 || ws_size < 170u * 1024u * 1024u) {
    const void* xsrc = (ix >= 0) ? d_in[ix] : d_in[0];
    xcopy_kernel<<<dim3(NROW * DIN / 256), 256, 0, stream>>>(xsrc, d_out);
    return;
  }

  const void *pK1, *pQ1, *pV1, *pK2, *pQ2, *pV2, *pG1, *pG2;
  if (wgp[0] == 0 && wgp[1] == 1) {                       // alphabetical
    pK1 = d_in[sixp[0]]; pK2 = d_in[sixp[1]];
    pQ1 = d_in[sixp[2]]; pQ2 = d_in[sixp[3]];
    pV1 = d_in[sixp[4]]; pV2 = d_in[sixp[5]];
    pG1 = d_in[wgp[0]];  pG2 = d_in[wgp[1]];
  } else if (wgp[0] == 3 && wgp[1] == 7) {                // reversed dict
    pV2 = d_in[sixp[0]]; pQ2 = d_in[sixp[1]]; pK2 = d_in[sixp[2]];
    pV1 = d_in[sixp[3]]; pQ1 = d_in[sixp[4]]; pK1 = d_in[sixp[5]];
    pG2 = d_in[wgp[0]];  pG1 = d_in[wgp[1]];
  } else {                                                // dict
    pK1 = d_in[sixp[0]]; pQ1 = d_in[sixp[1]]; pV1 = d_in[sixp[2]];
    pK2 = d_in[sixp[3]]; pQ2 = d_in[sixp[4]]; pV2 = d_in[sixp[5]];
    pG1 = d_in[wgp[0]];  pG2 = d_in[wgp[1]];
  }
  const void* input_x = d_in[ix];
  const void* box     = d_in[ib];

  char* ws = (char*)d_ws;
  size_t off = 0;
  auto alloc = [&](size_t bytes) { char* p = ws + off; off += (bytes + 255) & ~size_t(255); return p; };

  const size_t M_BYTES  = (size_t)NROW * DH * 2;

  bf16* Xb    = (bf16*)alloc((size_t)NROW * DIN * 2);
  bf16* Boxb  = (bf16*)alloc((size_t)NROW * DBOX * 2);
  bf16* Wcat1 = (bf16*)alloc((size_t)768 * DIN * 2);
  bf16* Wcat2 = (bf16*)alloc((size_t)768 * DIN * 2);
  bf16* K1 = (bf16*)alloc(M_BYTES);
  bf16* Q1 = (bf16*)alloc(M_BYTES);
  bf16* K2 = (bf16*)alloc(M_BYTES);
  bf16* Q2 = (bf16*)alloc(M_BYTES);
  bf16* VT1 = (bf16*)alloc(M_BYTES);
  bf16* VT2 = (bf16*)alloc(M_BYTES);
  float* M1 = (float*)alloc(DBOX * DBOX * 4);
  float* M2 = (float*)alloc(DBOX * DBOX * 4);
  bf16* P1   = (bf16*)alloc((size_t)NROW * 32 * 2);
  bf16* P2   = (bf16*)alloc((size_t)NROW * 32 * 2);
  bf16* Boxp = (bf16*)alloc((size_t)NROW * 32 * 2);
  float* sums = (float*)alloc(256);
  float* Up = (float*)alloc((size_t)2 * KSPL * NROW * DH * 4);   // 32 MB partials

  (void)hipMemsetAsync(sums, 0, 256, stream);

  PrepArgs pra;
  pra.src[0] = input_x; pra.dst[0] = Xb;
  pra.src[1] = box;     pra.dst[1] = Boxb;
  pra.wsrc[0] = pK1; pra.wdst[0] = Wcat1;
  pra.wsrc[1] = pQ1; pra.wdst[1] = Wcat1 + (size_t)256 * DIN;
  pra.wsrc[2] = pV1; pra.wdst[2] = Wcat1 + (size_t)512 * DIN;
  pra.wsrc[3] = pK2; pra.wdst[3] = Wcat2;
  pra.wsrc[4] = pQ2; pra.wdst[4] = Wcat2 + (size_t)256 * DIN;
  pra.wsrc[5] = pV2; pra.wdst[5] = Wcat2 + (size_t)512 * DIN;
  pra.wgsrc[0] = pG1; pra.M[0] = M1;
  pra.wgsrc[1] = pG2; pra.M[1] = M2;
  prep_kernel<<<dim3(8738), 256, 0, stream>>>(pra);

  PPArgs ppa;
  ppa.M[0] = M1; ppa.M[1] = M2;
  ppa.Boxb = Boxb;
  ppa.P[0] = P1; ppa.P[1] = P2;
  ppa.Boxp = Boxp;
  p_prep_kernel<<<dim3(512, 2), 256, 0, stream>>>(ppa);

  ProjArgs pa;
  pa.Wcat[0] = Wcat1; pa.Wcat[1] = Wcat2;
  pa.CK[0] = K1; pa.CQ[0] = Q1; pa.VT[0] = VT1;
  pa.CK[1] = K2; pa.CQ[1] = Q2; pa.VT[1] = VT2;
  proj_kernel<<<dim3(32, 6, 2), 256, 0, stream>>>(Xb, pa);

  FuseArgs fa;
  fa.K[0] = K1;  fa.K[1] = K2;
  fa.Q[0] = Q1;  fa.Q[1] = Q2;
  fa.VT[0] = VT1; fa.VT[1] = VT2;
  fa.P[0] = P1;  fa.P[1] = P2;
  fa.B = Boxp;
  fa.Up = Up;
  fa.sum = sums;
  fused_kernel<<<dim3(256), 512, 0, stream>>>(fa);

  epilogue_kernel<<<dim3(NROW * DIN / 256), 256, 0, stream>>>(input_x, Up, sums, d_out);
}

// Round 12
// 189.994 us; speedup vs baseline: 1.2955x; 1.2955x over previous
//
#include <hip/hip_runtime.h>
#include <hip/hip_bf16.h>
#include <hip/hip_fp16.h>

using bf16 = __hip_bfloat16;
typedef __attribute__((ext_vector_type(8))) short short8;
typedef __attribute__((ext_vector_type(4))) float f32x4;

#define NROW 4096
#define DIN  512
#define DH   256
#define DBOX 22
#define BKU  64    // proj k-tile
#define KSPL 4     // fused j-splits

#define NORM_LO 118
#define NORM_HI 130
#define WT_LO   110
#define WT_HI   126

static __device__ __forceinline__ f32x4 mfma16(short8 a, short8 b, f32x4 c) {
  return __builtin_amdgcn_mfma_f32_16x16x32_bf16(a, b, c, 0, 0, 0);
}
static __device__ __forceinline__ short8 ldg8(const bf16* p) {
  return *reinterpret_cast<const short8*>(p);
}
// async global->LDS, 16B per lane; lds ptr wave-uniform (HW adds lane*16)
static __device__ __forceinline__ void gll16(const bf16* g, void* lds) {
  __builtin_amdgcn_global_load_lds(
      (const __attribute__((address_space(1))) void*)g,
      (__attribute__((address_space(3))) void*)lds, 16, 0, 0);
}

// ---- per-block dtype detection: 0=fp32, 1=bf16, 2=fp16 -----------------------
static __device__ int detect_mode(const void* src, int lo, int hi) {
  __shared__ int cLo, cHi;
  if (threadIdx.x == 0) { cLo = 0; cHi = 0; }
  __syncthreads();
  const unsigned* w = (const unsigned*)src;
  int l = 0, h = 0;
  for (int t = threadIdx.x; t < 1024; t += 256) {
    unsigned v = w[t];
    int elo = (int)((v >> 7) & 0xFF);
    int ehi = (int)((v >> 23) & 0xFF);
    l += (elo >= lo && elo <= hi) ? 1 : 0;
    h += (ehi >= lo && ehi <= hi) ? 1 : 0;
  }
#pragma unroll
  for (int off = 32; off > 0; off >>= 1) {
    l += __shfl_down(l, off, 64);
    h += __shfl_down(h, off, 64);
  }
  if ((threadIdx.x & 63) == 0) { atomicAdd(&cLo, l); atomicAdd(&cHi, h); }
  __syncthreads();
  int lowCnt = cLo, hiCnt = cHi;
  __syncthreads();
  if (lowCnt > 700) return 1;
  if (hiCnt  > 700) return 0;
  return 2;
}

static __device__ __forceinline__ float load_as_float(const void* src, long i, int mode) {
  if (mode == 1) return __bfloat162float(((const bf16*)src)[i]);
  if (mode == 0) return ((const float*)src)[i];
  return __half2float(((const __half*)src)[i]);
}

static __device__ __forceinline__ void store_as(void* dst, long i, float v, int mode) {
  if (mode == 1)      ((bf16*)dst)[i]   = __float2bfloat16(v);
  else if (mode == 2) ((__half*)dst)[i] = __float2half(v);
  else                ((float*)dst)[i]  = v;
}

// ---------------- prep: convert x/box + weight transpose + M (22x22 Gram) -----
// blocks [0,8544): elementwise convert x, box -> bf16
// blocks [8544,8736): LDS-tiled transpose+convert W[512][256] -> WT[256][512]
// blocks [8736,8780): M[z][r][*] -- ONE block per (z,row): thread k holds
//   WG[r][k]; 22 coalesced column loads + shfl/LDS reduction. (R11 had this
//   in 2 blocks with a 256-deep serial scalar chain -> 84us critical path.)
struct PrepArgs {
  const void* src[2]; bf16* dst[2];      // convert segments (x, box)
  const void* wsrc[6]; bf16* wdst[6];    // transpose segments
  const void* wgsrc[2]; float* M[2];     // raw WG -> Gram matrix
};

__global__ __launch_bounds__(256) void prep_kernel(PrepArgs a) {
  __shared__ float tile[64][65];
  if (blockIdx.x < 8544) {
    int b = blockIdx.x, seg, base;
    if (b < 8192) { seg = 0; base = b; }
    else          { seg = 1; base = b - 8192; }
    int mode = detect_mode(a.src[seg], NORM_LO, NORM_HI);
    int i = base * 256 + threadIdx.x;
    a.dst[seg][i] = __float2bfloat16(load_as_float(a.src[seg], i, mode));
  } else if (blockIdx.x < 8736) {
    int b2 = blockIdx.x - 8544;
    const int which = b2 >> 5;          // 0..5
    int rem = b2 & 31;
    const int tr = (rem & 7) * 64;
    const int tc = (rem >> 3) * 64;
    int mode = detect_mode(a.wsrc[which], WT_LO, WT_HI);
    const int rin = threadIdx.x >> 6;
    const int cin = threadIdx.x & 63;
#pragma unroll
    for (int p = 0; p < 16; ++p) {
      int r = rin + p * 4;
      tile[r][cin] = load_as_float(a.wsrc[which], (long)(tr + r) * DH + tc + cin, mode);
    }
    __syncthreads();
#pragma unroll
    for (int p = 0; p < 16; ++p) {
      int r = rin + p * 4;
      a.wdst[which][(long)(tc + r) * DIN + tr + cin] = __float2bfloat16(tile[cin][r]);
    }
  } else {
    const int bi = blockIdx.x - 8736;
    const int z = bi / DBOX;            // 0..1
    const int r = bi % DBOX;            // 0..21
    int mode = detect_mode(a.wgsrc[z], WT_LO, WT_HI);
    const int k = threadIdx.x;          // 0..255 == DH
    float* red = (float*)tile;
    float wr = load_as_float(a.wgsrc[z], (long)r * DH + k, mode);
    for (int c = 0; c < DBOX; ++c) {
      float p = wr * load_as_float(a.wgsrc[z], (long)c * DH + k, mode);
#pragma unroll
      for (int off = 32; off > 0; off >>= 1) p += __shfl_down(p, off, 64);
      if ((k & 63) == 0) red[k >> 6] = p;
      __syncthreads();
      if (k == 0) a.M[z][r * DBOX + c] = red[0] + red[1] + red[2] + red[3];
      __syncthreads();
    }
  }
}

// ---------------- projections: C = X @ Wcat^T, Wcat = [K|Q|V] rows [768x512] ---
struct ProjArgs { const bf16* Wcat[2]; bf16* CK[2]; bf16* CQ[2]; bf16* VT[2]; };

__global__ __launch_bounds__(256, 3) void proj_kernel(const bf16* __restrict__ X, ProjArgs a) {
  const int z = blockIdx.z;
  const bf16* __restrict__ W = a.Wcat[z];
  __shared__ __align__(16) bf16 Xa[128 * BKU], Wb[128 * BKU];
  const int tid = threadIdx.x;
  const int wave = tid >> 6, lane = tid & 63;
  const int quad = lane >> 4, l16 = lane & 15;
  const int i0 = blockIdx.x * 128, n0 = blockIdx.y * 128;
  const int rw = (wave & 1) * 64, cw = (wave >> 1) * 64;

  int soff[4], grow[4], gko[4];
#pragma unroll
  for (int c = 0; c < 4; ++c) {
    int m = c * 256 + tid;
    int row = m >> 3, chunk = m & 7;
    grow[c] = row; gko[c] = chunk * 8;
    soff[c] = row * BKU + ((chunk ^ (row & 7)) * 8);
  }

  short8 pf[8];
  auto load_tiles = [&](int k0) {
#pragma unroll
    for (int c = 0; c < 4; ++c) {
      pf[c]     = ldg8(X + (long)(i0 + grow[c]) * DIN + k0 + gko[c]);
      pf[c + 4] = ldg8(W + (long)(n0 + grow[c]) * DIN + k0 + gko[c]);
    }
  };

  f32x4 acc[4][4];
#pragma unroll
  for (int p = 0; p < 4; ++p)
#pragma unroll
    for (int q = 0; q < 4; ++q) acc[p][q] = (f32x4){0,0,0,0};

  load_tiles(0);
  for (int kt = 0; kt < DIN / BKU; ++kt) {
    __syncthreads();
#pragma unroll
    for (int c = 0; c < 4; ++c) {
      *(short8*)&Xa[soff[c]] = pf[c];
      *(short8*)&Wb[soff[c]] = pf[c + 4];
    }
    __syncthreads();
    if (kt + 1 < DIN / BKU) load_tiles((kt + 1) * BKU);

#pragma unroll
    for (int kk = 0; kk < 2; ++kk) {
      short8 ax[4];
#pragma unroll
      for (int ti = 0; ti < 4; ++ti) {
        int row = rw + ti * 16 + l16;
        ax[ti] = *(const short8*)&Xa[row * BKU + (((kk * 4 + quad) ^ (row & 7)) * 8)];
      }
#pragma unroll
      for (int tj = 0; tj < 4; ++tj) {
        int row = cw + tj * 16 + l16;
        short8 bw = *(const short8*)&Wb[row * BKU + (((kk * 4 + quad) ^ (row & 7)) * 8)];
#pragma unroll
        for (int ti = 0; ti < 4; ++ti) acc[ti][tj] = mfma16(ax[ti], bw, acc[ti][tj]);
      }
    }
  }

#pragma unroll
  for (int ti = 0; ti < 4; ++ti) {
#pragma unroll
    for (int tj = 0; tj < 4; ++tj) {
#pragma unroll
      for (int r = 0; r < 4; ++r) {
        int row = i0 + rw + ti * 16 + quad * 4 + r;
        int n = n0 + cw + tj * 16 + l16;
        float sc = (n < 512) ? 0.25f : 1.0f;   // fold score 1/16 into K,Q
        bf16 v = __float2bfloat16(acc[ti][tj][r] * sc);
        if (n < 256)      a.CK[z][(long)row * DH + n] = v;
        else if (n < 512) a.CQ[z][(long)row * DH + n - 256] = v;
        else              a.VT[z][(long)(n - 512) * NROW + row] = v;
      }
    }
  }
}

// ---------------- P = box @ M / 16 (M read from global; 2KB L2-resident) ------
struct PPArgs { const float* M[2]; const bf16* Boxb; bf16* P[2]; bf16* Boxp; };

__global__ __launch_bounds__(256) void p_prep_kernel(PPArgs a) {
  const int z = blockIdx.y;
  __shared__ float Ml[DBOX * DBOX];
  for (int t = threadIdx.x; t < DBOX * DBOX; t += 256) Ml[t] = a.M[z][t];
  __syncthreads();
  int idx = blockIdx.x * 256 + threadIdx.x;
  int r = idx >> 5, c = idx & 31;
  float val = 0.f;
  if (c < DBOX) {
#pragma unroll
    for (int k = 0; k < DBOX; ++k)
      val += __bfloat162float(a.Boxb[r * DBOX + k]) * Ml[k * DBOX + c];
  }
  a.P[z][idx] = __float2bfloat16(val * 0.0625f);
  if (z == 0)
    a.Boxp[idx] = (c < DBOX) ? a.Boxb[r * DBOX + c] : __float2bfloat16(0.f);
}

// ---------------- fused score+PV: 2-barrier GLL pipeline (R12 = R11 fused) -----
// R11's fused is kept byte-identical: full-tile Q/V double-buffer, one
// lgkm-only barrier (S publish, GLLs in flight) + one counted vmcnt(2)
// barrier per j-tile; KQ = 32 uninterrupted MFMA with K in registers;
// gate waits counted vmcnt(10). Inferred ~40-50us from R11 totals (masked
// in profile by the prep regression); this round measures it directly.
struct FuseArgs {
  const bf16 *K[2], *Q[2], *VT[2], *P[2];
  const bf16* B;
  float* Up;       // [2 z][KSPL][NROW*DH] fp32 partials
  float* sum;
};

__global__ __launch_bounds__(512, 1) void fused_kernel(FuseArgs a) {
  const int bid = blockIdx.x;
  const int wl  = (bid & 7) * 32 + (bid >> 3);   // 256 = 8*32, bijective XCD swz
  const int ib  = wl & 31;                       // 32 i-blocks of 128 rows
  const int grp = wl >> 5;                       // 8 groups: one per XCD
  const int ks  = grp & 3;                       // KSPL == 4
  const int z   = grp >> 2;

  const bf16* __restrict__ K  = a.K[z];
  const bf16* __restrict__ Q  = a.Q[z];
  const bf16* __restrict__ VT = a.VT[z];
  const bf16* __restrict__ P  = a.P[z];
  const bf16* __restrict__ B  = a.B;
  float* __restrict__ U = a.Up + ((size_t)(z * KSPL + ks)) * NROW * DH;

  __shared__ __align__(16) bf16 Qsh[2][64 * 256];   // 2x32 KB full-k dbuf (shared)
  __shared__ __align__(16) bf16 Vsh[2][256 * 64];   // 2x32 KB dbuf (shared)
  __shared__ __align__(16) bf16 Ssh[2][64 * 64];    // 2x8 KB (per team)
  __shared__ float wsum[8];

  const int tid  = threadIdx.x;
  const int wv   = tid >> 6, lane = tid & 63;
  const int quad = lane >> 4, l16 = lane & 15;
  const int team = wv >> 2, wt = wv & 3;
  const int wi = wt >> 1, wj = wt & 1;   // team-local KQ wave grid (i32 x j32)
  const int nw = wt * 64;                // PV n-slice per wave (within team)
  const int i0t = ib * 128 + team * 64;
  const int jbase = ks * (NROW / KSPL);  // ks*1024
  const int NT = (NROW / KSPL) / 64;     // 16 j-tiles

  // hoisted per-lane GLL source offsets (element units)
  int qoff[4], voff[4];
#pragma unroll
  for (int c = 0; c < 4; ++c) {
    int m = wv * 4 + c;                  // 0..31 (Qsh buf 32KB, 512B rows)
    int b = m * 1024 + lane * 16;
    int row = b >> 9, g = (b >> 4) & 31;
    qoff[c] = row * DH + ((g ^ (row & 7)) << 3);
  }
#pragma unroll
  for (int c = 0; c < 4; ++c) {
    int m = wv * 4 + c;                  // 0..31 (Vsh buf 32KB, 128B rows)
    int b = m * 1024 + lane * 16;
    int row = b >> 7, g = (b >> 4) & 7;
    voff[c] = row * NROW + ((g ^ (row & 7)) << 3);
  }
  const bf16* Qb = Q + (long)jbase * DH;
  const bf16* Vb = VT + jbase;

  // ---- prologue (order pinned: pfr, kreg, Q(0), V(0), bb(0))
  short8 pfr[2];
#pragma unroll
  for (int ti = 0; ti < 2; ++ti)
    pfr[ti] = ldg8(P + (long)(i0t + wi * 32 + ti * 16 + l16) * 32 + quad * 8);

  short8 kreg[2][8];
#pragma unroll
  for (int ti = 0; ti < 2; ++ti)
#pragma unroll
    for (int kt = 0; kt < 8; ++kt)
      kreg[ti][kt] = ldg8(K + (long)(i0t + wi * 32 + ti * 16 + l16) * DH +
                          kt * 32 + quad * 8);
  __builtin_amdgcn_sched_barrier(0);
#pragma unroll
  for (int c = 0; c < 4; ++c)            // Q(0) -> Qsh[0]
    gll16(Qb + qoff[c], (char*)Qsh + (wv * 4 + c) * 1024);
  __builtin_amdgcn_sched_barrier(0);
#pragma unroll
  for (int c = 0; c < 4; ++c)            // V(0) -> Vsh[0]
    gll16(Vb + voff[c], (char*)Vsh + (wv * 4 + c) * 1024);
  __builtin_amdgcn_sched_barrier(0);
  short8 bbc[2], bbn[2];
#pragma unroll
  for (int tj = 0; tj < 2; ++tj)
    bbc[tj] = ldg8(B + (long)(jbase + wj * 32 + tj * 16 + l16) * 32 + quad * 8);
  __builtin_amdgcn_sched_barrier(0);

  f32x4 acc[4][4];
#pragma unroll
  for (int p = 0; p < 4; ++p)
#pragma unroll
    for (int q = 0; q < 4; ++q) acc[p][q] = (f32x4){0, 0, 0, 0};
  float lsum = 0.f;

  // prologue drain: Q(0),V(0),kreg,pfr staged; bb(0) (2) stays in flight
  asm volatile("s_waitcnt vmcnt(2) lgkmcnt(0)" ::: "memory");
  __builtin_amdgcn_sched_barrier(0);
  __builtin_amdgcn_s_barrier();
  __builtin_amdgcn_sched_barrier(0);

  int cur = 0;
  for (int t = 0; t < NT; ++t) {
    const int jnext = ((t + 1) & (NT - 1)) * 64;
    const int nxt = cur ^ 1;

    // ---- issue ALL t+1 staging (8 gll + 2 loads per wave, order pinned)
#pragma unroll
    for (int c = 0; c < 4; ++c)
      gll16(Qb + (long)jnext * DH + qoff[c], (char*)Qsh + nxt * 32768 + (wv * 4 + c) * 1024);
    __builtin_amdgcn_sched_barrier(0);
#pragma unroll
    for (int c = 0; c < 4; ++c)
      gll16(Vb + jnext + voff[c], (char*)Vsh + nxt * 32768 + (wv * 4 + c) * 1024);
    __builtin_amdgcn_sched_barrier(0);
#pragma unroll
    for (int tj = 0; tj < 2; ++tj)
      bbn[tj] = ldg8(B + (long)(jbase + jnext + wj * 32 + tj * 16 + l16) * 32 + quad * 8);
    __builtin_amdgcn_sched_barrier(0);

    // ---- KQ full k256 from Qsh[cur] + kreg (32 MFMA, uninterrupted)
    f32x4 wa[2][2];
#pragma unroll
    for (int p = 0; p < 2; ++p) { wa[p][0] = (f32x4){0,0,0,0}; wa[p][1] = (f32x4){0,0,0,0}; }
#pragma unroll
    for (int kt = 0; kt < 8; ++kt) {
      short8 qfr[2];
#pragma unroll
      for (int tj = 0; tj < 2; ++tj) {
        int row = wj * 32 + tj * 16 + l16;
        qfr[tj] = *(const short8*)((const char*)Qsh + cur * 32768 + row * 512 +
                                   (((kt * 4 + quad) ^ (row & 7)) << 4));
      }
      __builtin_amdgcn_s_setprio(1);
#pragma unroll
      for (int tj = 0; tj < 2; ++tj)
#pragma unroll
        for (int ti = 0; ti < 2; ++ti)
          wa[tj][ti] = mfma16(qfr[tj], kreg[ti][kt], wa[tj][ti]);
      __builtin_amdgcn_s_setprio(0);
    }

    // ---- gate (needs bb(t): exactly 10 younger loads = Q'4+V'4+bbn2)
    asm volatile("s_waitcnt vmcnt(10)" ::: "memory");
    f32x4 gm[2][2];
#pragma unroll
    for (int tj = 0; tj < 2; ++tj)
#pragma unroll
      for (int ti = 0; ti < 2; ++ti)
        gm[tj][ti] = mfma16(bbc[tj], pfr[ti], (f32x4){0.f, 0.f, 0.f, 0.f});

    // ---- S epilogue -> Ssh[team] (cvt_pk + b64, swizzled)
#pragma unroll
    for (int tj = 0; tj < 2; ++tj)
#pragma unroll
      for (int ti = 0; ti < 2; ++ti) {
        float sv[4];
#pragma unroll
        for (int r = 0; r < 4; ++r) {
          float g = gm[tj][ti][r];
          g = (g > 0.f) ? g : 0.f;
          float s = g * __expf(fminf(wa[tj][ti][r], 30.f));
          s = fminf(s, 1e30f);
          lsum += s;
          sv[r] = s;
        }
        unsigned w0, w1;
        asm("v_cvt_pk_bf16_f32 %0, %1, %2" : "=v"(w0) : "v"(sv[0]), "v"(sv[1]));
        asm("v_cvt_pk_bf16_f32 %0, %1, %2" : "=v"(w1) : "v"(sv[2]), "v"(sv[3]));
        int i = wi * 32 + ti * 16 + l16;
        int g16 = wj * 4 + tj * 2 + (quad >> 1);
        uint2 wvv; wvv.x = w0; wvv.y = w1;
        *(uint2*)((char*)Ssh + team * 8192 + i * 128 +
                  ((g16 ^ (i & 7)) << 4) + (quad & 1) * 8) = wvv;
      }

    // ---- barrier 1: publish Ssh. lgkm ONLY -- GLLs for t+1 stay in flight.
    asm volatile("s_waitcnt lgkmcnt(0)" ::: "memory");
    __builtin_amdgcn_sched_barrier(0);
    __builtin_amdgcn_s_barrier();
    __builtin_amdgcn_sched_barrier(0);

    // ---- PV: acc[ti][tn] += S[team](rows i) x V[cur](rows n), contract 64 j
#pragma unroll
    for (int jc = 0; jc < 2; ++jc) {
      short8 vfr[4], sfr[4];
#pragma unroll
      for (int tn = 0; tn < 4; ++tn) {
        int row = nw + tn * 16 + l16;
        vfr[tn] = *(const short8*)((const char*)Vsh + cur * 32768 + row * 128 +
                                   (((jc * 4 + quad) ^ (row & 7)) << 4));
      }
#pragma unroll
      for (int ti = 0; ti < 4; ++ti) {
        int row = ti * 16 + l16;
        sfr[ti] = *(const short8*)((const char*)Ssh + team * 8192 + row * 128 +
                                   (((jc * 4 + quad) ^ (row & 7)) << 4));
      }
      __builtin_amdgcn_s_setprio(1);
#pragma unroll
      for (int tn = 0; tn < 4; ++tn)
#pragma unroll
        for (int ti = 0; ti < 4; ++ti)
          acc[ti][tn] = mfma16(sfr[ti], vfr[tn], acc[ti][tn]);
      __builtin_amdgcn_s_setprio(0);
    }

    // ---- barrier 2: t+1 Q/V staged (2 younger = bbn); tile reads drained
    asm volatile("s_waitcnt vmcnt(2) lgkmcnt(0)" ::: "memory");
    __builtin_amdgcn_sched_barrier(0);
    __builtin_amdgcn_s_barrier();
    __builtin_amdgcn_sched_barrier(0);

    bbc[0] = bbn[0]; bbc[1] = bbn[1];
    cur = nxt;
  }

  // ---- write fp32 partial (disjoint tile, plain stores)
#pragma unroll
  for (int ti = 0; ti < 4; ++ti)
#pragma unroll
    for (int tn = 0; tn < 4; ++tn)
#pragma unroll
      for (int r = 0; r < 4; ++r)
        U[(long)(i0t + ti * 16 + quad * 4 + r) * DH + nw + tn * 16 + l16] =
            acc[ti][tn][r];

  // ---- global sum
#pragma unroll
  for (int off = 32; off > 0; off >>= 1) lsum += __shfl_down(lsum, off, 64);
  if (lane == 0) wsum[wv] = lsum;
  __syncthreads();
  if (tid == 0) {
    float s = 0.f;
#pragma unroll
    for (int w = 0; w < 8; ++w) s += wsum[w];
    atomicAdd(a.sum + z, s);
  }
}

// ---------------- epilogue: out = clamp(0.1*sum_ks(Up)/sum_b) + x --------------
__global__ __launch_bounds__(256) void epilogue_kernel(
    const void* __restrict__ xraw, const float* __restrict__ Up,
    const float* __restrict__ sums, void* __restrict__ out) {
  int mode = detect_mode(xraw, NORM_LO, NORM_HI);
  int idx = blockIdx.x * 256 + threadIdx.x;
  int r = idx >> 9, c = idx & 511;
  int z = (c < 256) ? 0 : 1;
  long e = (long)r * DH + (c & 255);
  const float* base = Up + (size_t)z * KSPL * NROW * DH;
  float u = 0.f;
#pragma unroll
  for (int ks = 0; ks < KSPL; ++ks) u += base[(size_t)ks * NROW * DH + e];
  float s = sums[z];
  float fr = u * 0.1f / s;
  fr = (fr == fr) ? fminf(fmaxf(fr, -0.05f), 0.05f) : 0.f;
  float xv = load_as_float(xraw, idx, mode);
  store_as(out, idx, xv + fr, mode);
}

// ---------------- fallback: out = cast(x), dtype-matched ----------------------
__global__ __launch_bounds__(256) void xcopy_kernel(const void* __restrict__ xraw,
                                                    void* __restrict__ out) {
  int mode = detect_mode(xraw, NORM_LO, NORM_HI);
  int idx = blockIdx.x * 256 + threadIdx.x;
  store_as(out, idx, load_as_float(xraw, idx, mode), mode);
}

// -------------------------------------------------------------------------------
extern "C" void kernel_launch(void* const* d_in, const int* in_sizes, int n_in,
                              void* d_out, int out_size, void* d_ws, size_t ws_size,
                              hipStream_t stream) {
  int ix = -1, ib = -1, wgp[2] = {-1, -1}, sixp[6] = {-1,-1,-1,-1,-1,-1};
  int nwg = 0, nsix = 0;
  for (int i = 0; i < n_in; ++i) {
    int s = in_sizes[i];
    if (s == NROW * DIN) ix = i;
    else if (s == NROW * DBOX) ib = i;
    else if (s == DIN * DH && nsix < 6) sixp[nsix++] = i;
    else if (s == DBOX * DH && nwg < 2) wgp[nwg++] = i;
  }

  if (ix < 0 || ib < 0 || nsix != 6 || nwg != 2 || ws_size < 170u * 1024u * 1024u) {
    const void* xsrc = (ix >= 0) ? d_in[ix] : d_in[0];
    xcopy_kernel<<<dim3(NROW * DIN / 256), 256, 0, stream>>>(xsrc, d_out);
    return;
  }

  const void *pK1, *pQ1, *pV1, *pK2, *pQ2, *pV2, *pG1, *pG2;
  if (wgp[0] == 0 && wgp[1] == 1) {                       // alphabetical
    pK1 = d_in[sixp[0]]; pK2 = d_in[sixp[1]];
    pQ1 = d_in[sixp[2]]; pQ2 = d_in[sixp[3]];
    pV1 = d_in[sixp[4]]; pV2 = d_in[sixp[5]];
    pG1 = d_in[wgp[0]];  pG2 = d_in[wgp[1]];
  } else if (wgp[0] == 3 && wgp[1] == 7) {                // reversed dict
    pV2 = d_in[sixp[0]]; pQ2 = d_in[sixp[1]]; pK2 = d_in[sixp[2]];
    pV1 = d_in[sixp[3]]; pQ1 = d_in[sixp[4]]; pK1 = d_in[sixp[5]];
    pG2 = d_in[wgp[0]];  pG1 = d_in[wgp[1]];
  } else {                                                // dict
    pK1 = d_in[sixp[0]]; pQ1 = d_in[sixp[1]]; pV1 = d_in[sixp[2]];
    pK2 = d_in[sixp[3]]; pQ2 = d_in[sixp[4]]; pV2 = d_in[sixp[5]];
    pG1 = d_in[wgp[0]];  pG2 = d_in[wgp[1]];
  }
  const void* input_x = d_in[ix];
  const void* box     = d_in[ib];

  char* ws = (char*)d_ws;
  size_t off = 0;
  auto alloc = [&](size_t bytes) { char* p = ws + off; off += (bytes + 255) & ~size_t(255); return p; };

  const size_t M_BYTES  = (size_t)NROW * DH * 2;

  bf16* Xb    = (bf16*)alloc((size_t)NROW * DIN * 2);
  bf16* Boxb  = (bf16*)alloc((size_t)NROW * DBOX * 2);
  bf16* Wcat1 = (bf16*)alloc((size_t)768 * DIN * 2);
  bf16* Wcat2 = (bf16*)alloc((size_t)768 * DIN * 2);
  bf16* K1 = (bf16*)alloc(M_BYTES);
  bf16* Q1 = (bf16*)alloc(M_BYTES);
  bf16* K2 = (bf16*)alloc(M_BYTES);
  bf16* Q2 = (bf16*)alloc(M_BYTES);
  bf16* VT1 = (bf16*)alloc(M_BYTES);
  bf16* VT2 = (bf16*)alloc(M_BYTES);
  float* M1 = (float*)alloc(DBOX * DBOX * 4);
  float* M2 = (float*)alloc(DBOX * DBOX * 4);
  bf16* P1   = (bf16*)alloc((size_t)NROW * 32 * 2);
  bf16* P2   = (bf16*)alloc((size_t)NROW * 32 * 2);
  bf16* Boxp = (bf16*)alloc((size_t)NROW * 32 * 2);
  float* sums = (float*)alloc(256);
  float* Up = (float*)alloc((size_t)2 * KSPL * NROW * DH * 4);   // 32 MB partials

  (void)hipMemsetAsync(sums, 0, 256, stream);

  PrepArgs pra;
  pra.src[0] = input_x; pra.dst[0] = Xb;
  pra.src[1] = box;     pra.dst[1] = Boxb;
  pra.wsrc[0] = pK1; pra.wdst[0] = Wcat1;
  pra.wsrc[1] = pQ1; pra.wdst[1] = Wcat1 + (size_t)256 * DIN;
  pra.wsrc[2] = pV1; pra.wdst[2] = Wcat1 + (size_t)512 * DIN;
  pra.wsrc[3] = pK2; pra.wdst[3] = Wcat2;
  pra.wsrc[4] = pQ2; pra.wdst[4] = Wcat2 + (size_t)256 * DIN;
  pra.wsrc[5] = pV2; pra.wdst[5] = Wcat2 + (size_t)512 * DIN;
  pra.wgsrc[0] = pG1; pra.M[0] = M1;
  pra.wgsrc[1] = pG2; pra.M[1] = M2;
  prep_kernel<<<dim3(8780), 256, 0, stream>>>(pra);

  PPArgs ppa;
  ppa.M[0] = M1; ppa.M[1] = M2;
  ppa.Boxb = Boxb;
  ppa.P[0] = P1; ppa.P[1] = P2;
  ppa.Boxp = Boxp;
  p_prep_kernel<<<dim3(512, 2), 256, 0, stream>>>(ppa);

  ProjArgs pa;
  pa.Wcat[0] = Wcat1; pa.Wcat[1] = Wcat2;
  pa.CK[0] = K1; pa.CQ[0] = Q1; pa.VT[0] = VT1;
  pa.CK[1] = K2; pa.CQ[1] = Q2; pa.VT[1] = VT2;
  proj_kernel<<<dim3(32, 6, 2), 256, 0, stream>>>(Xb, pa);

  FuseArgs fa;
  fa.K[0] = K1;  fa.K[1] = K2;
  fa.Q[0] = Q1;  fa.Q[1] = Q2;
  fa.VT[0] = VT1; fa.VT[1] = VT2;
  fa.P[0] = P1;  fa.P[1] = P2;
  fa.B = Boxp;
  fa.Up = Up;
  fa.sum = sums;
  fused_kernel<<<dim3(256), 512, 0, stream>>>(fa);

  epilogue_kernel<<<dim3(NROW * DIN / 256), 256, 0, stream>>>(input_x, Up, sums, d_out);
}

// Round 14
// 183.411 us; speedup vs baseline: 1.3420x; 1.0359x over previous
//
#include <hip/hip_runtime.h>
#include <hip/hip_bf16.h>
#include <hip/hip_fp16.h>

using bf16 = __hip_bfloat16;
typedef __attribute__((ext_vector_type(8))) short short8;
typedef __attribute__((ext_vector_type(4))) float f32x4;

#define NROW 4096
#define DIN  512
#define DH   256
#define DBOX 22
#define BKU  64    // proj k-tile
#define KSPL 4     // fused j-splits

#define NORM_LO 118
#define NORM_HI 130
#define WT_LO   110
#define WT_HI   126

static __device__ __forceinline__ f32x4 mfma16(short8 a, short8 b, f32x4 c) {
  return __builtin_amdgcn_mfma_f32_16x16x32_bf16(a, b, c, 0, 0, 0);
}
static __device__ __forceinline__ short8 ldg8(const bf16* p) {
  return *reinterpret_cast<const short8*>(p);
}
// async global->LDS, 16B per lane; lds ptr wave-uniform (HW adds lane*16)
static __device__ __forceinline__ void gll16(const bf16* g, void* lds) {
  __builtin_amdgcn_global_load_lds(
      (const __attribute__((address_space(1))) void*)g,
      (__attribute__((address_space(3))) void*)lds, 16, 0, 0);
}

// ---- per-block dtype detection: 0=fp32, 1=bf16, 2=fp16 -----------------------
static __device__ int detect_mode(const void* src, int lo, int hi) {
  __shared__ int cLo, cHi;
  if (threadIdx.x == 0) { cLo = 0; cHi = 0; }
  __syncthreads();
  const unsigned* w = (const unsigned*)src;
  int l = 0, h = 0;
  for (int t = threadIdx.x; t < 1024; t += 256) {
    unsigned v = w[t];
    int elo = (int)((v >> 7) & 0xFF);
    int ehi = (int)((v >> 23) & 0xFF);
    l += (elo >= lo && elo <= hi) ? 1 : 0;
    h += (ehi >= lo && ehi <= hi) ? 1 : 0;
  }
#pragma unroll
  for (int off = 32; off > 0; off >>= 1) {
    l += __shfl_down(l, off, 64);
    h += __shfl_down(h, off, 64);
  }
  if ((threadIdx.x & 63) == 0) { atomicAdd(&cLo, l); atomicAdd(&cHi, h); }
  __syncthreads();
  int lowCnt = cLo, hiCnt = cHi;
  __syncthreads();
  if (lowCnt > 700) return 1;
  if (hiCnt  > 700) return 0;
  return 2;
}

static __device__ __forceinline__ float load_as_float(const void* src, long i, int mode) {
  if (mode == 1) return __bfloat162float(((const bf16*)src)[i]);
  if (mode == 0) return ((const float*)src)[i];
  return __half2float(((const __half*)src)[i]);
}

static __device__ __forceinline__ void store_as(void* dst, long i, float v, int mode) {
  if (mode == 1)      ((bf16*)dst)[i]   = __float2bfloat16(v);
  else if (mode == 2) ((__half*)dst)[i] = __float2half(v);
  else                ((float*)dst)[i]  = v;
}

// ---------------- prep: convert x/box (x8 vectorized) + wtrans + Gram ----------
// blocks [0,1024):   x convert, 8 elems/thread (vectorized loads per mode)
// blocks [1024,1068): box convert, 8 elems/thread (90112 = 44*256*8)
// blocks [1068,1260): LDS-tiled transpose W[512][256] -> WT[256][512] (192)
// blocks [1260,1304): M[z][r][*] Gram row per block (44), shfl-reduced
struct PrepArgs {
  const void* src[2]; bf16* dst[2];      // convert segments (x, box)
  const void* wsrc[6]; bf16* wdst[6];    // transpose segments
  const void* wgsrc[2]; float* M[2];     // raw WG -> Gram matrix
};

__global__ __launch_bounds__(256) void prep_kernel(PrepArgs a) {
  __shared__ float tile[64][65];
  if (blockIdx.x < 1068) {
    int seg, base;
    if (blockIdx.x < 1024) { seg = 0; base = blockIdx.x; }
    else                   { seg = 1; base = blockIdx.x - 1024; }
    int mode = detect_mode(a.src[seg], NORM_LO, NORM_HI);
    long i0 = ((long)base * 256 + threadIdx.x) * 8;
    bf16 tmp[8];
    if (mode == 1) {
      short8 v = *(const short8*)((const bf16*)a.src[seg] + i0);
      *(short8*)((char*)(a.dst[seg] + i0)) = v;
      return;
    } else if (mode == 0) {
      const float4* f = (const float4*)((const float*)a.src[seg] + i0);
      float4 v0 = f[0], v1 = f[1];
      tmp[0] = __float2bfloat16(v0.x); tmp[1] = __float2bfloat16(v0.y);
      tmp[2] = __float2bfloat16(v0.z); tmp[3] = __float2bfloat16(v0.w);
      tmp[4] = __float2bfloat16(v1.x); tmp[5] = __float2bfloat16(v1.y);
      tmp[6] = __float2bfloat16(v1.z); tmp[7] = __float2bfloat16(v1.w);
    } else {
      short8 h = *(const short8*)((const __half*)a.src[seg] + i0);
#pragma unroll
      for (int j = 0; j < 8; ++j) {
        unsigned short us = (unsigned short)h[j];        // by value, no addr-of
        tmp[j] = __float2bfloat16(__half2float(__ushort_as_half(us)));
      }
    }
    *(short8*)((char*)(a.dst[seg] + i0)) = *(short8*)tmp;
  } else if (blockIdx.x < 1260) {
    int b2 = blockIdx.x - 1068;
    const int which = b2 >> 5;          // 0..5
    int rem = b2 & 31;
    const int tr = (rem & 7) * 64;
    const int tc = (rem >> 3) * 64;
    int mode = detect_mode(a.wsrc[which], WT_LO, WT_HI);
    const int rin = threadIdx.x >> 6;
    const int cin = threadIdx.x & 63;
#pragma unroll
    for (int p = 0; p < 16; ++p) {
      int r = rin + p * 4;
      tile[r][cin] = load_as_float(a.wsrc[which], (long)(tr + r) * DH + tc + cin, mode);
    }
    __syncthreads();
#pragma unroll
    for (int p = 0; p < 16; ++p) {
      int r = rin + p * 4;
      a.wdst[which][(long)(tc + r) * DIN + tr + cin] = __float2bfloat16(tile[cin][r]);
    }
  } else {
    const int bi = blockIdx.x - 1260;
    const int z = bi / DBOX;            // 0..1
    const int r = bi % DBOX;            // 0..21
    int mode = detect_mode(a.wgsrc[z], WT_LO, WT_HI);
    const int k = threadIdx.x;          // 0..255 == DH
    float* red = (float*)tile;
    float wr = load_as_float(a.wgsrc[z], (long)r * DH + k, mode);
    for (int c = 0; c < DBOX; ++c) {
      float p = wr * load_as_float(a.wgsrc[z], (long)c * DH + k, mode);
#pragma unroll
      for (int off = 32; off > 0; off >>= 1) p += __shfl_down(p, off, 64);
      if ((k & 63) == 0) red[k >> 6] = p;
      __syncthreads();
      if (k == 0) a.M[z][r * DBOX + c] = red[0] + red[1] + red[2] + red[3];
      __syncthreads();
    }
  }
}

// ---------------- proj (+merged P-prep): 1D grid, 384 proj + 1024 P blocks -----
// proj: C = X @ Wcat^T, Wcat = [K|Q|V] rows [768x512]; K,Q pre-scaled 0.25.
// P blocks (b>=384): P = box @ M / 16 (M from prep, 2KB L2-resident) + Boxp.
// Both depend only on prep outputs; fused consumes both -> one launch saved.
struct ProjArgs {
  const bf16* Wcat[2]; bf16* CK[2]; bf16* CQ[2]; bf16* VT[2];
  const float* M[2]; const bf16* Boxb; bf16* P[2]; bf16* Boxp;
};

__global__ __launch_bounds__(256, 3) void proj_kernel(const bf16* __restrict__ X, ProjArgs a) {
  __shared__ __align__(16) bf16 Xa[128 * BKU], Wb[128 * BKU];
  if (blockIdx.x >= 384) {
    // ---- merged p_prep block
    const int idx5 = blockIdx.x - 384;   // 0..1023
    const int z = idx5 >> 9;
    const int pb = idx5 & 511;
    float* Ml = (float*)Xa;
    for (int t = threadIdx.x; t < DBOX * DBOX; t += 256) Ml[t] = a.M[z][t];
    __syncthreads();
    int idx = pb * 256 + threadIdx.x;
    int r = idx >> 5, c = idx & 31;
    float val = 0.f;
    if (c < DBOX) {
#pragma unroll
      for (int k = 0; k < DBOX; ++k)
        val += __bfloat162float(a.Boxb[r * DBOX + k]) * Ml[k * DBOX + c];
    }
    a.P[z][idx] = __float2bfloat16(val * 0.0625f);
    if (z == 0)
      a.Boxp[idx] = (c < DBOX) ? a.Boxb[r * DBOX + c] : __float2bfloat16(0.f);
    return;
  }
  const int z = blockIdx.x / 192;
  const int rem = blockIdx.x % 192;
  const int by = rem >> 5, bx = rem & 31;
  const bf16* __restrict__ W = a.Wcat[z];
  const int tid = threadIdx.x;
  const int wave = tid >> 6, lane = tid & 63;
  const int quad = lane >> 4, l16 = lane & 15;
  const int i0 = bx * 128, n0 = by * 128;
  const int rw = (wave & 1) * 64, cw = (wave >> 1) * 64;

  int soff[4], grow[4], gko[4];
#pragma unroll
  for (int c = 0; c < 4; ++c) {
    int m = c * 256 + tid;
    int row = m >> 3, chunk = m & 7;
    grow[c] = row; gko[c] = chunk * 8;
    soff[c] = row * BKU + ((chunk ^ (row & 7)) * 8);
  }

  short8 pf[8];
  auto load_tiles = [&](int k0) {
#pragma unroll
    for (int c = 0; c < 4; ++c) {
      pf[c]     = ldg8(X + (long)(i0 + grow[c]) * DIN + k0 + gko[c]);
      pf[c + 4] = ldg8(W + (long)(n0 + grow[c]) * DIN + k0 + gko[c]);
    }
  };

  f32x4 acc[4][4];
#pragma unroll
  for (int p = 0; p < 4; ++p)
#pragma unroll
    for (int q = 0; q < 4; ++q) acc[p][q] = (f32x4){0,0,0,0};

  load_tiles(0);
  for (int kt = 0; kt < DIN / BKU; ++kt) {
    __syncthreads();
#pragma unroll
    for (int c = 0; c < 4; ++c) {
      *(short8*)&Xa[soff[c]] = pf[c];
      *(short8*)&Wb[soff[c]] = pf[c + 4];
    }
    __syncthreads();
    if (kt + 1 < DIN / BKU) load_tiles((kt + 1) * BKU);

#pragma unroll
    for (int kk = 0; kk < 2; ++kk) {
      short8 ax[4];
#pragma unroll
      for (int ti = 0; ti < 4; ++ti) {
        int row = rw + ti * 16 + l16;
        ax[ti] = *(const short8*)&Xa[row * BKU + (((kk * 4 + quad) ^ (row & 7)) * 8)];
      }
#pragma unroll
      for (int tj = 0; tj < 4; ++tj) {
        int row = cw + tj * 16 + l16;
        short8 bw = *(const short8*)&Wb[row * BKU + (((kk * 4 + quad) ^ (row & 7)) * 8)];
#pragma unroll
        for (int ti = 0; ti < 4; ++ti) acc[ti][tj] = mfma16(ax[ti], bw, acc[ti][tj]);
      }
    }
  }

#pragma unroll
  for (int ti = 0; ti < 4; ++ti) {
#pragma unroll
    for (int tj = 0; tj < 4; ++tj) {
#pragma unroll
      for (int r = 0; r < 4; ++r) {
        int row = i0 + rw + ti * 16 + quad * 4 + r;
        int n = n0 + cw + tj * 16 + l16;
        float sc = (n < 512) ? 0.25f : 1.0f;   // fold score 1/16 into K,Q
        bf16 v = __float2bfloat16(acc[ti][tj][r] * sc);
        if (n < 256)      a.CK[z][(long)row * DH + n] = v;
        else if (n < 512) a.CQ[z][(long)row * DH + n - 256] = v;
        else              a.VT[z][(long)(n - 512) * NROW + row] = v;
      }
    }
  }
}

// ---------------- fused score+PV: 2-barrier GLL pipeline (frozen R12 kernel) ---
struct FuseArgs {
  const bf16 *K[2], *Q[2], *VT[2], *P[2];
  const bf16* B;
  float* Up;       // [2 z][KSPL][NROW*DH] fp32 partials
  float* sum;
};

__global__ __launch_bounds__(512, 1) void fused_kernel(FuseArgs a) {
  const int bid = blockIdx.x;
  const int wl  = (bid & 7) * 32 + (bid >> 3);   // 256 = 8*32, bijective XCD swz
  const int ib  = wl & 31;                       // 32 i-blocks of 128 rows
  const int grp = wl >> 5;                       // 8 groups: one per XCD
  const int ks  = grp & 3;                       // KSPL == 4
  const int z   = grp >> 2;

  const bf16* __restrict__ K  = a.K[z];
  const bf16* __restrict__ Q  = a.Q[z];
  const bf16* __restrict__ VT = a.VT[z];
  const bf16* __restrict__ P  = a.P[z];
  const bf16* __restrict__ B  = a.B;
  float* __restrict__ U = a.Up + ((size_t)(z * KSPL + ks)) * NROW * DH;

  __shared__ __align__(16) bf16 Qsh[2][64 * 256];   // 2x32 KB full-k dbuf (shared)
  __shared__ __align__(16) bf16 Vsh[2][256 * 64];   // 2x32 KB dbuf (shared)
  __shared__ __align__(16) bf16 Ssh[2][64 * 64];    // 2x8 KB (per team)
  __shared__ float wsum[8];

  const int tid  = threadIdx.x;
  const int wv   = tid >> 6, lane = tid & 63;
  const int quad = lane >> 4, l16 = lane & 15;
  const int team = wv >> 2, wt = wv & 3;
  const int wi = wt >> 1, wj = wt & 1;   // team-local KQ wave grid (i32 x j32)
  const int nw = wt * 64;                // PV n-slice per wave (within team)
  const int i0t = ib * 128 + team * 64;
  const int jbase = ks * (NROW / KSPL);  // ks*1024
  const int NT = (NROW / KSPL) / 64;     // 16 j-tiles

  // hoisted per-lane GLL source offsets (element units)
  int qoff[4], voff[4];
#pragma unroll
  for (int c = 0; c < 4; ++c) {
    int m = wv * 4 + c;                  // 0..31 (Qsh buf 32KB, 512B rows)
    int b = m * 1024 + lane * 16;
    int row = b >> 9, g = (b >> 4) & 31;
    qoff[c] = row * DH + ((g ^ (row & 7)) << 3);
  }
#pragma unroll
  for (int c = 0; c < 4; ++c) {
    int m = wv * 4 + c;                  // 0..31 (Vsh buf 32KB, 128B rows)
    int b = m * 1024 + lane * 16;
    int row = b >> 7, g = (b >> 4) & 7;
    voff[c] = row * NROW + ((g ^ (row & 7)) << 3);
  }
  const bf16* Qb = Q + (long)jbase * DH;
  const bf16* Vb = VT + jbase;

  // ---- prologue (order pinned: pfr, kreg, Q(0), V(0), bb(0))
  short8 pfr[2];
#pragma unroll
  for (int ti = 0; ti < 2; ++ti)
    pfr[ti] = ldg8(P + (long)(i0t + wi * 32 + ti * 16 + l16) * 32 + quad * 8);

  short8 kreg[2][8];
#pragma unroll
  for (int ti = 0; ti < 2; ++ti)
#pragma unroll
    for (int kt = 0; kt < 8; ++kt)
      kreg[ti][kt] = ldg8(K + (long)(i0t + wi * 32 + ti * 16 + l16) * DH +
                          kt * 32 + quad * 8);
  __builtin_amdgcn_sched_barrier(0);
#pragma unroll
  for (int c = 0; c < 4; ++c)            // Q(0) -> Qsh[0]
    gll16(Qb + qoff[c], (char*)Qsh + (wv * 4 + c) * 1024);
  __builtin_amdgcn_sched_barrier(0);
#pragma unroll
  for (int c = 0; c < 4; ++c)            // V(0) -> Vsh[0]
    gll16(Vb + voff[c], (char*)Vsh + (wv * 4 + c) * 1024);
  __builtin_amdgcn_sched_barrier(0);
  short8 bbc[2], bbn[2];
#pragma unroll
  for (int tj = 0; tj < 2; ++tj)
    bbc[tj] = ldg8(B + (long)(jbase + wj * 32 + tj * 16 + l16) * 32 + quad * 8);
  __builtin_amdgcn_sched_barrier(0);

  f32x4 acc[4][4];
#pragma unroll
  for (int p = 0; p < 4; ++p)
#pragma unroll
    for (int q = 0; q < 4; ++q) acc[p][q] = (f32x4){0, 0, 0, 0};
  float lsum = 0.f;

  // prologue drain: Q(0),V(0),kreg,pfr staged; bb(0) (2) stays in flight
  asm volatile("s_waitcnt vmcnt(2) lgkmcnt(0)" ::: "memory");
  __builtin_amdgcn_sched_barrier(0);
  __builtin_amdgcn_s_barrier();
  __builtin_amdgcn_sched_barrier(0);

  int cur = 0;
  for (int t = 0; t < NT; ++t) {
    const int jnext = ((t + 1) & (NT - 1)) * 64;
    const int nxt = cur ^ 1;

    // ---- issue ALL t+1 staging (8 gll + 2 loads per wave, order pinned)
#pragma unroll
    for (int c = 0; c < 4; ++c)
      gll16(Qb + (long)jnext * DH + qoff[c], (char*)Qsh + nxt * 32768 + (wv * 4 + c) * 1024);
    __builtin_amdgcn_sched_barrier(0);
#pragma unroll
    for (int c = 0; c < 4; ++c)
      gll16(Vb + jnext + voff[c], (char*)Vsh + nxt * 32768 + (wv * 4 + c) * 1024);
    __builtin_amdgcn_sched_barrier(0);
#pragma unroll
    for (int tj = 0; tj < 2; ++tj)
      bbn[tj] = ldg8(B + (long)(jbase + jnext + wj * 32 + tj * 16 + l16) * 32 + quad * 8);
    __builtin_amdgcn_sched_barrier(0);

    // ---- KQ full k256 from Qsh[cur] + kreg (32 MFMA, uninterrupted)
    f32x4 wa[2][2];
#pragma unroll
    for (int p = 0; p < 2; ++p) { wa[p][0] = (f32x4){0,0,0,0}; wa[p][1] = (f32x4){0,0,0,0}; }
#pragma unroll
    for (int kt = 0; kt < 8; ++kt) {
      short8 qfr[2];
#pragma unroll
      for (int tj = 0; tj < 2; ++tj) {
        int row = wj * 32 + tj * 16 + l16;
        qfr[tj] = *(const short8*)((const char*)Qsh + cur * 32768 + row * 512 +
                                   (((kt * 4 + quad) ^ (row & 7)) << 4));
      }
      __builtin_amdgcn_s_setprio(1);
#pragma unroll
      for (int tj = 0; tj < 2; ++tj)
#pragma unroll
        for (int ti = 0; ti < 2; ++ti)
          wa[tj][ti] = mfma16(qfr[tj], kreg[ti][kt], wa[tj][ti]);
      __builtin_amdgcn_s_setprio(0);
    }

    // ---- gate (needs bb(t): exactly 10 younger loads = Q'4+V'4+bbn2)
    asm volatile("s_waitcnt vmcnt(10)" ::: "memory");
    f32x4 gm[2][2];
#pragma unroll
    for (int tj = 0; tj < 2; ++tj)
#pragma unroll
      for (int ti = 0; ti < 2; ++ti)
        gm[tj][ti] = mfma16(bbc[tj], pfr[ti], (f32x4){0.f, 0.f, 0.f, 0.f});

    // ---- S epilogue -> Ssh[team] (cvt_pk + b64, swizzled)
#pragma unroll
    for (int tj = 0; tj < 2; ++tj)
#pragma unroll
      for (int ti = 0; ti < 2; ++ti) {
        float sv[4];
#pragma unroll
        for (int r = 0; r < 4; ++r) {
          float g = gm[tj][ti][r];
          g = (g > 0.f) ? g : 0.f;
          float s = g * __expf(fminf(wa[tj][ti][r], 30.f));
          s = fminf(s, 1e30f);
          lsum += s;
          sv[r] = s;
        }
        unsigned w0, w1;
        asm("v_cvt_pk_bf16_f32 %0, %1, %2" : "=v"(w0) : "v"(sv[0]), "v"(sv[1]));
        asm("v_cvt_pk_bf16_f32 %0, %1, %2" : "=v"(w1) : "v"(sv[2]), "v"(sv[3]));
        int i = wi * 32 + ti * 16 + l16;
        int g16 = wj * 4 + tj * 2 + (quad >> 1);
        uint2 wvv; wvv.x = w0; wvv.y = w1;
        *(uint2*)((char*)Ssh + team * 8192 + i * 128 +
                  ((g16 ^ (i & 7)) << 4) + (quad & 1) * 8) = wvv;
      }

    // ---- barrier 1: publish Ssh. lgkm ONLY -- GLLs for t+1 stay in flight.
    asm volatile("s_waitcnt lgkmcnt(0)" ::: "memory");
    __builtin_amdgcn_sched_barrier(0);
    __builtin_amdgcn_s_barrier();
    __builtin_amdgcn_sched_barrier(0);

    // ---- PV: acc[ti][tn] += S[team](rows i) x V[cur](rows n), contract 64 j
#pragma unroll
    for (int jc = 0; jc < 2; ++jc) {
      short8 vfr[4], sfr[4];
#pragma unroll
      for (int tn = 0; tn < 4; ++tn) {
        int row = nw + tn * 16 + l16;
        vfr[tn] = *(const short8*)((const char*)Vsh + cur * 32768 + row * 128 +
                                   (((jc * 4 + quad) ^ (row & 7)) << 4));
      }
#pragma unroll
      for (int ti = 0; ti < 4; ++ti) {
        int row = ti * 16 + l16;
        sfr[ti] = *(const short8*)((const char*)Ssh + team * 8192 + row * 128 +
                                   (((jc * 4 + quad) ^ (row & 7)) << 4));
      }
      __builtin_amdgcn_s_setprio(1);
#pragma unroll
      for (int tn = 0; tn < 4; ++tn)
#pragma unroll
        for (int ti = 0; ti < 4; ++ti)
          acc[ti][tn] = mfma16(sfr[ti], vfr[tn], acc[ti][tn]);
      __builtin_amdgcn_s_setprio(0);
    }

    // ---- barrier 2: t+1 Q/V staged (2 younger = bbn); tile reads drained
    asm volatile("s_waitcnt vmcnt(2) lgkmcnt(0)" ::: "memory");
    __builtin_amdgcn_sched_barrier(0);
    __builtin_amdgcn_s_barrier();
    __builtin_amdgcn_sched_barrier(0);

    bbc[0] = bbn[0]; bbc[1] = bbn[1];
    cur = nxt;
  }

  // ---- write fp32 partial (disjoint tile, plain stores)
#pragma unroll
  for (int ti = 0; ti < 4; ++ti)
#pragma unroll
    for (int tn = 0; tn < 4; ++tn)
#pragma unroll
      for (int r = 0; r < 4; ++r)
        U[(long)(i0t + ti * 16 + quad * 4 + r) * DH + nw + tn * 16 + l16] =
            acc[ti][tn][r];

  // ---- global sum
#pragma unroll
  for (int off = 32; off > 0; off >>= 1) lsum += __shfl_down(lsum, off, 64);
  if (lane == 0) wsum[wv] = lsum;
  __syncthreads();
  if (tid == 0) {
    float s = 0.f;
#pragma unroll
    for (int w = 0; w < 8; ++w) s += wsum[w];
    atomicAdd(a.sum + z, s);
  }
}

// ---------------- epilogue (x4 vectorized): out = clamp(0.1*sumUp/sum) + x -----
__global__ __launch_bounds__(256) void epilogue_kernel(
    const void* __restrict__ xraw, const float* __restrict__ Up,
    const float* __restrict__ sums, void* __restrict__ out) {
  int mode = detect_mode(xraw, NORM_LO, NORM_HI);
  long idx = ((long)blockIdx.x * 256 + threadIdx.x) * 4;
  int r = (int)(idx >> 9), c = (int)(idx & 511);
  int z = (c < 256) ? 0 : 1;                 // 4-aligned c stays in one half
  long e = (long)r * DH + (c & 255);
  const float* base = Up + (size_t)z * KSPL * NROW * DH;
  float u0 = 0.f, u1 = 0.f, u2 = 0.f, u3 = 0.f;
#pragma unroll
  for (int ks = 0; ks < KSPL; ++ks) {
    float4 v = *(const float4*)(base + (size_t)ks * NROW * DH + e);
    u0 += v.x; u1 += v.y; u2 += v.z; u3 += v.w;
  }
  float s = sums[z];
  float uu[4] = {u0, u1, u2, u3};
#pragma unroll
  for (int j = 0; j < 4; ++j) {
    float fr = uu[j] * 0.1f / s;
    fr = (fr == fr) ? fminf(fmaxf(fr, -0.05f), 0.05f) : 0.f;
    float xv = load_as_float(xraw, idx + j, mode);
    store_as(out, idx + j, xv + fr, mode);
  }
}

// ---------------- fallback: out = cast(x), dtype-matched ----------------------
__global__ __launch_bounds__(256) void xcopy_kernel(const void* __restrict__ xraw,
                                                    void* __restrict__ out) {
  int mode = detect_mode(xraw, NORM_LO, NORM_HI);
  int idx = blockIdx.x * 256 + threadIdx.x;
  store_as(out, idx, load_as_float(xraw, idx, mode), mode);
}

// -------------------------------------------------------------------------------
extern "C" void kernel_launch(void* const* d_in, const int* in_sizes, int n_in,
                              void* d_out, int out_size, void* d_ws, size_t ws_size,
                              hipStream_t stream) {
  int ix = -1, ib = -1, wgp[2] = {-1, -1}, sixp[6] = {-1,-1,-1,-1,-1,-1};
  int nwg = 0, nsix = 0;
  for (int i = 0; i < n_in; ++i) {
    int s = in_sizes[i];
    if (s == NROW * DIN) ix = i;
    else if (s == NROW * DBOX) ib = i;
    else if (s == DIN * DH && nsix < 6) sixp[nsix++] = i;
    else if (s == DBOX * DH && nwg < 2) wgp[nwg++] = i;
  }

  if (ix < 0 || ib < 0 || nsix != 6 || nwg != 2 || ws_size < 170u * 1024u * 1024u) {
    const void* xsrc = (ix >= 0) ? d_in[ix] : d_in[0];
    xcopy_kernel<<<dim3(NROW * DIN / 256), 256, 0, stream>>>(xsrc, d_out);
    return;
  }

  const void *pK1, *pQ1, *pV1, *pK2, *pQ2, *pV2, *pG1, *pG2;
  if (wgp[0] == 0 && wgp[1] == 1) {                       // alphabetical
    pK1 = d_in[sixp[0]]; pK2 = d_in[sixp[1]];
    pQ1 = d_in[sixp[2]]; pQ2 = d_in[sixp[3]];
    pV1 = d_in[sixp[4]]; pV2 = d_in[sixp[5]];
    pG1 = d_in[wgp[0]];  pG2 = d_in[wgp[1]];
  } else if (wgp[0] == 3 && wgp[1] == 7) {                // reversed dict
    pV2 = d_in[sixp[0]]; pQ2 = d_in[sixp[1]]; pK2 = d_in[sixp[2]];
    pV1 = d_in[sixp[3]]; pQ1 = d_in[sixp[4]]; pK1 = d_in[sixp[5]];
    pG2 = d_in[wgp[0]];  pG1 = d_in[wgp[1]];
  } else {                                                // dict
    pK1 = d_in[sixp[0]]; pQ1 = d_in[sixp[1]]; pV1 = d_in[sixp[2]];
    pK2 = d_in[sixp[3]]; pQ2 = d_in[sixp[4]]; pV2 = d_in[sixp[5]];
    pG1 = d_in[wgp[0]];  pG2 = d_in[wgp[1]];
  }
  const void* input_x = d_in[ix];
  const void* box     = d_in[ib];

  char* ws = (char*)d_ws;
  size_t off = 0;
  auto alloc = [&](size_t bytes) { char* p = ws + off; off += (bytes + 255) & ~size_t(255); return p; };

  const size_t M_BYTES  = (size_t)NROW * DH * 2;

  bf16* Xb    = (bf16*)alloc((size_t)NROW * DIN * 2);
  bf16* Boxb  = (bf16*)alloc((size_t)NROW * DBOX * 2);
  bf16* Wcat1 = (bf16*)alloc((size_t)768 * DIN * 2);
  bf16* Wcat2 = (bf16*)alloc((size_t)768 * DIN * 2);
  bf16* K1 = (bf16*)alloc(M_BYTES);
  bf16* Q1 = (bf16*)alloc(M_BYTES);
  bf16* K2 = (bf16*)alloc(M_BYTES);
  bf16* Q2 = (bf16*)alloc(M_BYTES);
  bf16* VT1 = (bf16*)alloc(M_BYTES);
  bf16* VT2 = (bf16*)alloc(M_BYTES);
  float* M1 = (float*)alloc(DBOX * DBOX * 4);
  float* M2 = (float*)alloc(DBOX * DBOX * 4);
  bf16* P1   = (bf16*)alloc((size_t)NROW * 32 * 2);
  bf16* P2   = (bf16*)alloc((size_t)NROW * 32 * 2);
  bf16* Boxp = (bf16*)alloc((size_t)NROW * 32 * 2);
  float* sums = (float*)alloc(256);
  float* Up = (float*)alloc((size_t)2 * KSPL * NROW * DH * 4);   // 32 MB partials

  (void)hipMemsetAsync(sums, 0, 256, stream);

  PrepArgs pra;
  pra.src[0] = input_x; pra.dst[0] = Xb;
  pra.src[1] = box;     pra.dst[1] = Boxb;
  pra.wsrc[0] = pK1; pra.wdst[0] = Wcat1;
  pra.wsrc[1] = pQ1; pra.wdst[1] = Wcat1 + (size_t)256 * DIN;
  pra.wsrc[2] = pV1; pra.wdst[2] = Wcat1 + (size_t)512 * DIN;
  pra.wsrc[3] = pK2; pra.wdst[3] = Wcat2;
  pra.wsrc[4] = pQ2; pra.wdst[4] = Wcat2 + (size_t)256 * DIN;
  pra.wsrc[5] = pV2; pra.wdst[5] = Wcat2 + (size_t)512 * DIN;
  pra.wgsrc[0] = pG1; pra.M[0] = M1;
  pra.wgsrc[1] = pG2; pra.M[1] = M2;
  prep_kernel<<<dim3(1304), 256, 0, stream>>>(pra);

  ProjArgs pa;
  pa.Wcat[0] = Wcat1; pa.Wcat[1] = Wcat2;
  pa.CK[0] = K1; pa.CQ[0] = Q1; pa.VT[0] = VT1;
  pa.CK[1] = K2; pa.CQ[1] = Q2; pa.VT[1] = VT2;
  pa.M[0] = M1; pa.M[1] = M2;
  pa.Boxb = Boxb;
  pa.P[0] = P1; pa.P[1] = P2;
  pa.Boxp = Boxp;
  proj_kernel<<<dim3(384 + 1024), 256, 0, stream>>>(Xb, pa);

  FuseArgs fa;
  fa.K[0] = K1;  fa.K[1] = K2;
  fa.Q[0] = Q1;  fa.Q[1] = Q2;
  fa.VT[0] = VT1; fa.VT[1] = VT2;
  fa.P[0] = P1;  fa.P[1] = P2;
  fa.B = Boxp;
  fa.Up = Up;
  fa.sum = sums;
  fused_kernel<<<dim3(256), 512, 0, stream>>>(fa);

  epilogue_kernel<<<dim3(NROW * DIN / (256 * 4)), 256, 0, stream>>>(input_x, Up, sums, d_out);
}